// Round 1
// baseline (693.859 us; speedup 1.0000x reference)
//
#include <hip/hip_runtime.h>

#define NG   64
#define N1i  65
#define BPTS 262144

__global__ __launch_bounds__(256) void trilerp_kernel(
    const float*  __restrict__ x,       // (B,3)
    const float*  __restrict__ gv,      // (N1^3, 1)
    const float4* __restrict__ gf,      // (N1^3, 256) viewed as (N1^3, 64) float4
    float*        __restrict__ outv,    // (B,1)
    float4*       __restrict__ outf)    // (B,256) viewed as (B,64) float4
{
    const int lane = threadIdx.x & 63;
    const int p    = blockIdx.x * 4 + (threadIdx.x >> 6);

    // Load the point (same 3 floats across the wave -> broadcast from cache)
    const float px = x[3 * p + 0];
    const float py = x[3 * p + 1];
    const float pz = x[3 * p + 2];

    const float rx = (px + 1.0f) * 32.0f;
    const float ry = (py + 1.0f) * 32.0f;
    const float rz = (pz + 1.0f) * 32.0f;

    const bool valid = (rx >= 0.0f) & (rx <= 64.0f) &
                       (ry >= 0.0f) & (ry <= 64.0f) &
                       (rz >= 0.0f) & (rz <= 64.0f);

    int ix = (int)floorf(rx); ix = min(max(ix, 0), NG - 1);
    int iy = (int)floorf(ry); iy = min(max(iy, 0), NG - 1);
    int iz = (int)floorf(rz); iz = min(max(iz, 0), NG - 1);

    const float tx = rx - (float)ix;
    const float ty = ry - (float)iy;
    const float tz = rz - (float)iz;

    const int base = (ix * N1i + iy) * N1i + iz;

    const float wx0 = 1.0f - tx, wy0 = 1.0f - ty, wz0 = 1.0f - tz;
    float w[8];
    w[0] = wx0 * wy0 * wz0;   // (0,0,0)
    w[1] = wx0 * wy0 * tz;    // (0,0,1)
    w[2] = wx0 * ty  * wz0;   // (0,1,0)
    w[3] = wx0 * ty  * tz;    // (0,1,1)
    w[4] = tx  * wy0 * wz0;   // (1,0,0)
    w[5] = tx  * wy0 * tz;    // (1,0,1)
    w[6] = tx  * ty  * wz0;   // (1,1,0)
    w[7] = tx  * ty  * tz;    // (1,1,1)

    const int off[8] = {0, 1, N1i, N1i + 1,
                        N1i * N1i, N1i * N1i + 1, N1i * N1i + N1i, N1i * N1i + N1i + 1};

    float4 acc = make_float4(0.f, 0.f, 0.f, 0.f);
#pragma unroll
    for (int c = 0; c < 8; ++c) {
        const float4 v = gf[(size_t)(base + off[c]) * 64 + lane];
        acc.x += w[c] * v.x;
        acc.y += w[c] * v.y;
        acc.z += w[c] * v.z;
        acc.w += w[c] * v.w;
    }
    if (!valid) acc = make_float4(0.f, 0.f, 0.f, 0.f);
    outf[(size_t)p * 64 + lane] = acc;

    if (lane == 0) {
        float s = 0.0f;
#pragma unroll
        for (int c = 0; c < 8; ++c) s += w[c] * gv[base + off[c]];
        outv[p] = valid ? s : 0.0f;
    }
}

extern "C" void kernel_launch(void* const* d_in, const int* in_sizes, int n_in,
                              void* d_out, int out_size, void* d_ws, size_t ws_size,
                              hipStream_t stream) {
    const float*  x  = (const float*)d_in[0];
    const float*  gv = (const float*)d_in[1];
    const float4* gf = (const float4*)d_in[2];

    float*  outv = (float*)d_out;                 // first output: (B,1)
    float4* outf = (float4*)((float*)d_out + BPTS); // second output: (B,256)

    // 4 points per 256-thread block (one wave per point)
    trilerp_kernel<<<BPTS / 4, 256, 0, stream>>>(x, gv, gf, outv, outf);
}

// Round 2
// 615.448 us; speedup vs baseline: 1.1274x; 1.1274x over previous
//
#include <hip/hip_runtime.h>

#define NG   64
#define N1i  65
#define BPTS 262144
#define NBUCK 4096   // 16x16x16 coarse buckets (4x4x4 cells each)

__device__ __forceinline__ int point_bucket(const float* __restrict__ x, int p) {
    const float rx = (x[3 * p + 0] + 1.0f) * 32.0f;
    const float ry = (x[3 * p + 1] + 1.0f) * 32.0f;
    const float rz = (x[3 * p + 2] + 1.0f) * 32.0f;
    int ix = min(max((int)floorf(rx), 0), NG - 1) >> 2;
    int iy = min(max((int)floorf(ry), 0), NG - 1) >> 2;
    int iz = min(max((int)floorf(rz), 0), NG - 1) >> 2;
    return (ix * 16 + iy) * 16 + iz;
}

__global__ __launch_bounds__(256) void hist_kernel(
    const float* __restrict__ x, int* __restrict__ counts)
{
    const int p = blockIdx.x * 256 + threadIdx.x;
    atomicAdd(&counts[point_bucket(x, p)], 1);
}

__global__ __launch_bounds__(1024) void scan_kernel(
    const int* __restrict__ counts, int* __restrict__ offsets)
{
    __shared__ int sm[1024];
    const int t = threadIdx.x;
    const int c0 = counts[t * 4 + 0], c1 = counts[t * 4 + 1];
    const int c2 = counts[t * 4 + 2], c3 = counts[t * 4 + 3];
    const int s = c0 + c1 + c2 + c3;
    sm[t] = s;
    __syncthreads();
    int val = s;
    for (int off = 1; off < 1024; off <<= 1) {
        const int v = (t >= off) ? sm[t - off] : 0;
        __syncthreads();
        val += v;
        sm[t] = val;
        __syncthreads();
    }
    const int base = val - s;  // exclusive prefix
    offsets[t * 4 + 0] = base;
    offsets[t * 4 + 1] = base + c0;
    offsets[t * 4 + 2] = base + c0 + c1;
    offsets[t * 4 + 3] = base + c0 + c1 + c2;
}

__global__ __launch_bounds__(256) void scatter_kernel(
    const float* __restrict__ x, int* __restrict__ offsets, int* __restrict__ perm)
{
    const int p = blockIdx.x * 256 + threadIdx.x;
    const int pos = atomicAdd(&offsets[point_bucket(x, p)], 1);
    perm[pos] = p;
}

__global__ __launch_bounds__(256) void trilerp_kernel(
    const float*  __restrict__ x,       // (B,3)
    const float*  __restrict__ gv,      // (N1^3, 1)
    const float4* __restrict__ gf,      // (N1^3, 256) as (N1^3, 64) float4
    const int*    __restrict__ perm,    // sorted point order
    float*        __restrict__ outv,    // (B,1)
    float4*       __restrict__ outf)    // (B,256) as (B,64) float4
{
    const int lane = threadIdx.x & 63;
    const int slot = blockIdx.x * 4 + (threadIdx.x >> 6);
    const int p    = perm[slot];

    const float px = x[3 * p + 0];
    const float py = x[3 * p + 1];
    const float pz = x[3 * p + 2];

    const float rx = (px + 1.0f) * 32.0f;
    const float ry = (py + 1.0f) * 32.0f;
    const float rz = (pz + 1.0f) * 32.0f;

    const bool valid = (rx >= 0.0f) & (rx <= 64.0f) &
                       (ry >= 0.0f) & (ry <= 64.0f) &
                       (rz >= 0.0f) & (rz <= 64.0f);

    int ix = (int)floorf(rx); ix = min(max(ix, 0), NG - 1);
    int iy = (int)floorf(ry); iy = min(max(iy, 0), NG - 1);
    int iz = (int)floorf(rz); iz = min(max(iz, 0), NG - 1);

    const float tx = rx - (float)ix;
    const float ty = ry - (float)iy;
    const float tz = rz - (float)iz;

    const int base = (ix * N1i + iy) * N1i + iz;

    const float wx0 = 1.0f - tx, wy0 = 1.0f - ty, wz0 = 1.0f - tz;
    float w[8];
    w[0] = wx0 * wy0 * wz0;
    w[1] = wx0 * wy0 * tz;
    w[2] = wx0 * ty  * wz0;
    w[3] = wx0 * ty  * tz;
    w[4] = tx  * wy0 * wz0;
    w[5] = tx  * wy0 * tz;
    w[6] = tx  * ty  * wz0;
    w[7] = tx  * ty  * tz;

    const int off[8] = {0, 1, N1i, N1i + 1,
                        N1i * N1i, N1i * N1i + 1, N1i * N1i + N1i, N1i * N1i + N1i + 1};

    float4 acc = make_float4(0.f, 0.f, 0.f, 0.f);
#pragma unroll
    for (int c = 0; c < 8; ++c) {
        const float4 v = gf[(size_t)(base + off[c]) * 64 + lane];
        acc.x += w[c] * v.x;
        acc.y += w[c] * v.y;
        acc.z += w[c] * v.z;
        acc.w += w[c] * v.w;
    }
    if (!valid) acc = make_float4(0.f, 0.f, 0.f, 0.f);
    outf[(size_t)p * 64 + lane] = acc;

    if (lane == 0) {
        float s = 0.0f;
#pragma unroll
        for (int c = 0; c < 8; ++c) s += w[c] * gv[base + off[c]];
        outv[p] = valid ? s : 0.0f;
    }
}

extern "C" void kernel_launch(void* const* d_in, const int* in_sizes, int n_in,
                              void* d_out, int out_size, void* d_ws, size_t ws_size,
                              hipStream_t stream) {
    const float*  x  = (const float*)d_in[0];
    const float*  gv = (const float*)d_in[1];
    const float4* gf = (const float4*)d_in[2];

    float*  outv = (float*)d_out;                    // first output: (B,1)
    float4* outf = (float4*)((float*)d_out + BPTS);  // second output: (B,256)

    // workspace layout: [counts: 4096 ints][offsets: 4096 ints][perm: B ints]
    int* counts  = (int*)d_ws;
    int* offsets = counts + NBUCK;
    int* perm    = offsets + NBUCK;

    hipMemsetAsync(counts, 0, NBUCK * sizeof(int), stream);
    hist_kernel   <<<BPTS / 256, 256,  0, stream>>>(x, counts);
    scan_kernel   <<<1,          1024, 0, stream>>>(counts, offsets);
    scatter_kernel<<<BPTS / 256, 256,  0, stream>>>(x, offsets, perm);
    trilerp_kernel<<<BPTS / 4,   256,  0, stream>>>(x, gv, gf, perm, outv, outf);
}